// Round 1
// baseline (615.803 us; speedup 1.0000x reference)
//
#include <hip/hip_runtime.h>

#define F_ 8
#define C_ 128
#define H_ 96
#define W_ 96
#define P_ (H_*W_)   // 9216
#define I_ 64
#define T_ 17
#define KK_ (F_*T_)  // 136

// neighborhood offsets: t=0..8 dilation 1 (3x3), t=9..16 dilation 3 (3x3 minus center)
__constant__ int c_dy[T_] = {-1,-1,-1, 0,0,0, 1,1,1, -3,-3,-3, 0,0, 3,3,3};
__constant__ int c_dx[T_] = {-1, 0, 1,-1,0,1,-1,0,1, -3, 0, 3,-3,3,-3,0,3};

// ---- prep: vt[c] = sum_i wt[i]*rgb_theta_w[i,c]; u[c] = sum_i wp[i]*rgb_phi_w[i,c]
// ct[0] = sum_i wt[i]*rgb_theta_b[i]; ct[1] = sum_i wp[i]*rgb_phi_b[i]
__global__ __launch_bounds__(128) void k_prep(const float* __restrict__ rtw,
                                              const float* __restrict__ rpw,
                                              const float* __restrict__ rtb,
                                              const float* __restrict__ rpb,
                                              const float* __restrict__ cp,
                                              float* __restrict__ vt,
                                              float* __restrict__ u,
                                              float* __restrict__ ct) {
    int c = threadIdx.x;  // 128 threads
    float a = 0.f, b2 = 0.f;
    for (int i = 0; i < I_; ++i) {
        a  += cp[i]      * rtw[i*C_ + c];
        b2 += cp[I_ + i] * rpw[i*C_ + c];
    }
    vt[c] = a;
    u[c]  = b2;
    if (c == 0) { float s = 0.f; for (int i = 0; i < I_; ++i) s += cp[i]      * rtb[i]; ct[0] = s; }
    if (c == 1) { float s = 0.f; for (int i = 0; i < I_; ++i) s += cp[I_ + i] * rpb[i]; ct[1] = s; }
}

// generic small transpose: out[c*R + r] = in[r*Cc + c]
__global__ __launch_bounds__(256) void k_transpose(const float* __restrict__ in,
                                                   float* __restrict__ out, int R, int Cc) {
    int idx = blockIdx.x * 256 + threadIdx.x;
    if (idx < R * Cc) {
        int r = idx / Cc, c = idx % Cc;
        out[c * R + r] = in[idx];
    }
}

// conv1x1: out[f][i][p] = sum_c in[f][c][p] * wT[c][i] + b[i]   (layout [N][I][P])
__global__ __launch_bounds__(256) void k_conv(const float* __restrict__ in,
                                              const float* __restrict__ wT,
                                              const float* __restrict__ b,
                                              float* __restrict__ out) {
    int p  = blockIdx.x * 256 + threadIdx.x;
    int i0 = blockIdx.y * 32;
    int f  = blockIdx.z;
    const float* xp = in + (size_t)f * C_ * P_ + p;
    float acc[32];
#pragma unroll
    for (int ii = 0; ii < 32; ++ii) acc[ii] = 0.f;
    for (int c = 0; c < C_; ++c) {
        float xv = xp[(size_t)c * P_];
        const float* wr = wT + (size_t)c * I_ + i0;   // wave-uniform -> s_load
#pragma unroll
        for (int ii = 0; ii < 32; ++ii) acc[ii] += xv * wr[ii];
    }
    float* op = out + ((size_t)f * I_ + i0) * P_ + p;
#pragma unroll
    for (int ii = 0; ii < 32; ++ii) op[(size_t)ii * P_] = acc[ii] + b[i0 + ii];
}

// SR[p] = ct0 + sum_c rgb[c,p]*vt[c];  Bf[f][p] = ct1 + sum_c x[f,c,p]*u[c]
__global__ __launch_bounds__(256) void k_fields(const float* __restrict__ rgb,
                                                const float* __restrict__ x,
                                                const float* __restrict__ vt,
                                                const float* __restrict__ u,
                                                const float* __restrict__ ct,
                                                float* __restrict__ SR,
                                                float* __restrict__ Bf) {
    int p = blockIdx.x * 256 + threadIdx.x;
    float s = ct[0];
    for (int c = 0; c < C_; ++c) s += rgb[(size_t)c * P_ + p] * vt[c];
    SR[p] = s;
    float cb = ct[1];
    for (int f = 0; f < F_; ++f) {
        float b2 = cb;
        const float* xp = x + (size_t)f * C_ * P_ + p;
        for (int c = 0; c < C_; ++c) b2 += xp[(size_t)c * P_] * u[c];
        Bf[f * P_ + p] = b2;
    }
}

// scores: S[f1][k][p] = sum_i PH[f1][i][p] * TH[f2(k)][i][p+off(k)]   (0 if OOB)
__global__ __launch_bounds__(256) void k_scores(const float* __restrict__ PH,
                                                const float* __restrict__ TH,
                                                float* __restrict__ S) {
    int p  = blockIdx.x * 256 + threadIdx.x;
    int k0 = blockIdx.y * 4;
    int px = p % W_, py = p / W_;
    float acc[8][4];
#pragma unroll
    for (int a = 0; a < 8; ++a)
#pragma unroll
        for (int b = 0; b < 4; ++b) acc[a][b] = 0.f;
    int   qq[4];
    float msk[4];
    int   f2s[4];
#pragma unroll
    for (int kk = 0; kk < 4; ++kk) {
        int k  = k0 + kk;
        int f2 = k / T_;
        int t  = k - f2 * T_;
        int dy = c_dy[t], dx = c_dx[t];
        bool v = ((unsigned)(py + dy) < H_) && ((unsigned)(px + dx) < W_);
        int q  = p + dy * W_ + dx;
        q = min(max(q, 0), P_ - 1);   // clamped: always in-bounds, select 0 after
        qq[kk]  = q;
        msk[kk] = v ? 1.f : 0.f;
        f2s[kk] = f2;
    }
    for (int i = 0; i < I_; ++i) {
        float phv[8];
#pragma unroll
        for (int f1 = 0; f1 < 8; ++f1) phv[f1] = PH[((size_t)f1 * I_ + i) * P_ + p];
#pragma unroll
        for (int kk = 0; kk < 4; ++kk) {
            float tv = TH[((size_t)f2s[kk] * I_ + i) * P_ + qq[kk]] * msk[kk];
#pragma unroll
            for (int f1 = 0; f1 < 8; ++f1) acc[f1][kk] += phv[f1] * tv;
        }
    }
#pragma unroll
    for (int f1 = 0; f1 < 8; ++f1)
#pragma unroll
        for (int kk = 0; kk < 4; ++kk)
            S[((size_t)f1 * KK_ + k0 + kk) * P_ + p] = acc[f1][kk];
}

// softmax over k per (f1, p): write exp(v - max) in place, den = 1/sum
__global__ __launch_bounds__(256) void k_softmax(float* __restrict__ S,
                                                 float* __restrict__ den) {
    int p  = blockIdx.x * 256 + threadIdx.x;
    int f1 = blockIdx.y;
    float* sp = S + (size_t)f1 * KK_ * P_ + p;
    float m = -1e30f;
    for (int k = 0; k < KK_; ++k) m = fmaxf(m, sp[(size_t)k * P_]);
    float s = 0.f;
    for (int k = 0; k < KK_; ++k) {
        float e = __expf(sp[(size_t)k * P_] - m);
        sp[(size_t)k * P_] = e;
        s += e;
    }
    den[f1 * P_ + p] = 1.f / s;
}

// Y[f1][i][p] = (sum_k Sexp[f1][k][p] * G[f2(k)][i][p+off(k)]) * den[f1][p]
__global__ __launch_bounds__(256) void k_y(const float* __restrict__ S,
                                           const float* __restrict__ G,
                                           const float* __restrict__ den,
                                           float* __restrict__ Y) {
    int p   = blockIdx.x * 256 + threadIdx.x;
    int f10 = blockIdx.y * 4;
    int i0  = blockIdx.z * 8;
    int px = p % W_, py = p / W_;
    float acc[4][8];
#pragma unroll
    for (int a = 0; a < 4; ++a)
#pragma unroll
        for (int b = 0; b < 8; ++b) acc[a][b] = 0.f;
    for (int f2 = 0; f2 < F_; ++f2) {
        for (int t = 0; t < T_; ++t) {
            int k  = f2 * T_ + t;
            int dy = c_dy[t], dx = c_dx[t];
            bool v = ((unsigned)(py + dy) < H_) && ((unsigned)(px + dx) < W_);
            int q  = p + dy * W_ + dx;
            q = min(max(q, 0), P_ - 1);
            float m = v ? 1.f : 0.f;
            float av[4];
#pragma unroll
            for (int ff = 0; ff < 4; ++ff)
                av[ff] = S[((size_t)(f10 + ff) * KK_ + k) * P_ + p];
            float gv[8];
#pragma unroll
            for (int ii = 0; ii < 8; ++ii)
                gv[ii] = G[((size_t)f2 * I_ + i0 + ii) * P_ + q] * m;
#pragma unroll
            for (int ff = 0; ff < 4; ++ff)
#pragma unroll
                for (int ii = 0; ii < 8; ++ii) acc[ff][ii] += av[ff] * gv[ii];
        }
    }
#pragma unroll
    for (int ff = 0; ff < 4; ++ff) {
        float dv = den[(f10 + ff) * P_ + p];
#pragma unroll
        for (int ii = 0; ii < 8; ++ii)
            Y[((size_t)(f10 + ff) * I_ + i0 + ii) * P_ + p] = acc[ff][ii] * dv;
    }
}

// YR[f][i][p] = sum_t relu(SR[p+off]+Bf[f][p])/T * GR[i][p+off]   (0 OOB)
__global__ __launch_bounds__(256) void k_yr(const float* __restrict__ Bf,
                                            const float* __restrict__ SR,
                                            const float* __restrict__ GR,
                                            float* __restrict__ YR) {
    int p = blockIdx.x * 256 + threadIdx.x;
    int f = blockIdx.y;
    int px = p % W_, py = p / W_;
    float bv = Bf[f * P_ + p];
    float fr[T_];
    int   qs[T_];
#pragma unroll
    for (int t = 0; t < T_; ++t) {
        int dy = c_dy[t], dx = c_dx[t];
        bool v = ((unsigned)(py + dy) < H_) && ((unsigned)(px + dx) < W_);
        int q  = p + dy * W_ + dx;
        q = min(max(q, 0), P_ - 1);
        qs[t] = q;
        fr[t] = v ? fmaxf(SR[q] + bv, 0.f) * (1.f / (float)T_) : 0.f;
    }
    for (int i0 = 0; i0 < I_; i0 += 16) {
        float acc[16];
#pragma unroll
        for (int ii = 0; ii < 16; ++ii) acc[ii] = 0.f;
#pragma unroll
        for (int t = 0; t < T_; ++t) {
            const float* gp = GR + qs[t];
#pragma unroll
            for (int ii = 0; ii < 16; ++ii)
                acc[ii] += fr[t] * gp[(size_t)(i0 + ii) * P_];
        }
#pragma unroll
        for (int ii = 0; ii < 16; ++ii)
            YR[((size_t)f * I_ + i0 + ii) * P_ + p] = acc[ii];
    }
}

// out[f][c][p] = sum_i Y[f][i][p]*WT[i][c] + sum_i YR[f][i][p]*RWT[i][c] + Wb[c] + RWb[c] + x[f][c][p]
__global__ __launch_bounds__(256) void k_final(const float* __restrict__ Y,
                                               const float* __restrict__ YR,
                                               const float* __restrict__ WT,
                                               const float* __restrict__ Wb,
                                               const float* __restrict__ RWT,
                                               const float* __restrict__ RWb,
                                               const float* __restrict__ x,
                                               float* __restrict__ out) {
    int p  = blockIdx.x * 256 + threadIdx.x;
    int f  = blockIdx.y;
    int c0 = blockIdx.z * 32;
    float acc[32];
#pragma unroll
    for (int cc = 0; cc < 32; ++cc) acc[cc] = 0.f;
    const float* yp  = Y  + (size_t)f * I_ * P_ + p;
    const float* yrp = YR + (size_t)f * I_ * P_ + p;
    for (int i = 0; i < I_; ++i) {
        float yv  = yp[(size_t)i * P_];
        float yrv = yrp[(size_t)i * P_];
        const float* w1 = WT  + (size_t)i * C_ + c0;   // uniform -> s_load
        const float* w2 = RWT + (size_t)i * C_ + c0;
#pragma unroll
        for (int cc = 0; cc < 32; ++cc) acc[cc] += yv * w1[cc] + yrv * w2[cc];
    }
#pragma unroll
    for (int cc = 0; cc < 32; ++cc) {
        size_t o = ((size_t)f * C_ + c0 + cc) * P_ + p;
        out[o] = acc[cc] + Wb[c0 + cc] + RWb[c0 + cc] + x[o];
    }
}

extern "C" void kernel_launch(void* const* d_in, const int* in_sizes, int n_in,
                              void* d_out, int out_size, void* d_ws, size_t ws_size,
                              hipStream_t stream) {
    const float* x    = (const float*)d_in[0];
    const float* rgb  = (const float*)d_in[1];
    const float* g_w  = (const float*)d_in[2];
    const float* g_b  = (const float*)d_in[3];
    const float* th_w = (const float*)d_in[4];
    const float* th_b = (const float*)d_in[5];
    const float* ph_w = (const float*)d_in[6];
    const float* ph_b = (const float*)d_in[7];
    const float* W_w  = (const float*)d_in[8];
    const float* W_b  = (const float*)d_in[9];
    const float* rg_w = (const float*)d_in[10];
    const float* rg_b = (const float*)d_in[11];
    const float* rt_w = (const float*)d_in[12];
    // d_in[13] = rgb_theta_b
    const float* rt_b = (const float*)d_in[13];
    const float* rp_w = (const float*)d_in[14];
    const float* rp_b = (const float*)d_in[15];
    const float* rW_w = (const float*)d_in[16];
    const float* rW_b = (const float*)d_in[17];
    const float* cp_w = (const float*)d_in[18];
    float* out = (float*)d_out;

    const size_t FIP = (size_t)F_ * I_ * P_;   // 4718592
    const size_t SKP = (size_t)F_ * KK_ * P_;  // 10027008

    float* ws  = (float*)d_ws;
    float* G   = ws;
    float* TH  = G + FIP;
    float* PH  = TH + FIP;
    float* S   = PH + FIP;
    float* DEN = S + SKP;
    float* GR  = DEN + (size_t)F_ * P_;
    float* SR  = GR + (size_t)I_ * P_;
    float* Bf  = SR + P_;
    float* VT  = Bf + (size_t)F_ * P_;
    float* U   = VT + C_;
    float* CT  = U + C_;
    float* gT  = CT + 2;
    float* thT = gT  + (size_t)C_ * I_;
    float* phT = thT + (size_t)C_ * I_;
    float* rgT = phT + (size_t)C_ * I_;
    float* WT  = rgT + (size_t)C_ * I_;
    float* RWT = WT  + (size_t)C_ * I_;
    float* Y   = TH;   // alias: TH dead after k_scores
    float* YR  = PH;   // alias: PH dead after k_scores

    // prep + weight transposes
    k_prep<<<1, 128, 0, stream>>>(rt_w, rp_w, rt_b, rp_b, cp_w, VT, U, CT);
    k_transpose<<<32, 256, 0, stream>>>(g_w,  gT,  I_, C_);
    k_transpose<<<32, 256, 0, stream>>>(th_w, thT, I_, C_);
    k_transpose<<<32, 256, 0, stream>>>(ph_w, phT, I_, C_);
    k_transpose<<<32, 256, 0, stream>>>(rg_w, rgT, I_, C_);
    k_transpose<<<32, 256, 0, stream>>>(W_w,  WT,  C_, I_);
    k_transpose<<<32, 256, 0, stream>>>(rW_w, RWT, C_, I_);

    // convs: G, TH, PH on x; GR on rgb
    k_conv<<<dim3(P_ / 256, I_ / 32, F_), 256, 0, stream>>>(x, gT,  g_b,  G);
    k_conv<<<dim3(P_ / 256, I_ / 32, F_), 256, 0, stream>>>(x, thT, th_b, TH);
    k_conv<<<dim3(P_ / 256, I_ / 32, F_), 256, 0, stream>>>(x, phT, ph_b, PH);
    k_conv<<<dim3(P_ / 256, I_ / 32, 1),  256, 0, stream>>>(rgb, rgT, rg_b, GR);

    // scalar fields
    k_fields<<<P_ / 256, 256, 0, stream>>>(rgb, x, VT, U, CT, SR, Bf);

    // attention
    k_scores<<<dim3(P_ / 256, KK_ / 4), 256, 0, stream>>>(PH, TH, S);
    k_softmax<<<dim3(P_ / 256, F_), 256, 0, stream>>>(S, DEN);
    k_y<<<dim3(P_ / 256, F_ / 4, I_ / 8), 256, 0, stream>>>(S, G, DEN, Y);

    // rgb branch
    k_yr<<<dim3(P_ / 256, F_), 256, 0, stream>>>(Bf, SR, GR, YR);

    // final conv + residual
    k_final<<<dim3(P_ / 256, F_, C_ / 32), 256, 0, stream>>>(Y, YR, WT, W_b, RWT, rW_b, x, out);
}

// Round 2
// 425.442 us; speedup vs baseline: 1.4474x; 1.4474x over previous
//
#include <hip/hip_runtime.h>

#define F_ 8
#define C_ 128
#define H_ 96
#define W_ 96
#define P_ (H_*W_)   // 9216
#define I_ 64
#define T_ 17
#define KK_ (F_*T_)  // 136

__constant__ int c_dy[T_] = {-1,-1,-1, 0,0,0, 1,1,1, -3,-3,-3, 0,0, 3,3,3};
__constant__ int c_dx[T_] = {-1, 0, 1,-1,0,1,-1,0,1, -3, 0, 3,-3,3,-3,0,3};

// vt[c] = sum_i wt[i]*rtw[i,c]; u[c] = sum_i wp[i]*rpw[i,c];
// ct[0] = wt·rtb; ct[1] = wp·rpb; Kc[c] = sum_i rWw[c,i]*rg_b[i]
__global__ __launch_bounds__(128) void k_prep(const float* __restrict__ rtw,
                                              const float* __restrict__ rpw,
                                              const float* __restrict__ rtb,
                                              const float* __restrict__ rpb,
                                              const float* __restrict__ cp,
                                              const float* __restrict__ rWw,
                                              const float* __restrict__ rgb_,
                                              float* __restrict__ vt,
                                              float* __restrict__ u,
                                              float* __restrict__ ct,
                                              float* __restrict__ Kc) {
    int c = threadIdx.x;  // 128
    float a = 0.f, b2 = 0.f, kk = 0.f;
    for (int i = 0; i < I_; ++i) {
        a  += cp[i]      * rtw[i*C_ + c];
        b2 += cp[I_ + i] * rpw[i*C_ + c];
        kk += rWw[c*I_ + i] * rgb_[i];
    }
    vt[c] = a; u[c] = b2; Kc[c] = kk;
    if (c == 0) { float s = 0.f; for (int i = 0; i < I_; ++i) s += cp[i]      * rtb[i]; ct[0] = s; }
    if (c == 1) { float s = 0.f; for (int i = 0; i < I_; ++i) s += cp[I_ + i] * rpb[i]; ct[1] = s; }
}

// MT[cc][c] = sum_i rWw[c,i] * rgw[i,cc]   (transposed fused rgb->out matrix)
__global__ __launch_bounds__(128) void k_mt(const float* __restrict__ rWw,
                                            const float* __restrict__ rgw,
                                            float* __restrict__ MT) {
    int cc = blockIdx.x;   // 128 blocks
    int c  = threadIdx.x;  // 128 threads
    float s = 0.f;
    for (int i = 0; i < I_; ++i) s += rWw[c*I_ + i] * rgw[i*C_ + cc];
    MT[cc*C_ + c] = s;
}

// 4 weight transposes in one dispatch
__global__ __launch_bounds__(256) void k_tr(const float* __restrict__ g_w,
                                            const float* __restrict__ th_w,
                                            const float* __restrict__ ph_w,
                                            const float* __restrict__ W_w,
                                            float* __restrict__ gT,
                                            float* __restrict__ thT,
                                            float* __restrict__ phT,
                                            float* __restrict__ WT) {
    int which = blockIdx.y;
    int idx = blockIdx.x * 256 + threadIdx.x;  // 8192 per slice
    const float* src; float* dst; int Cc;
    if      (which == 0) { src = g_w;  dst = gT;  Cc = C_; }
    else if (which == 1) { src = th_w; dst = thT; Cc = C_; }
    else if (which == 2) { src = ph_w; dst = phT; Cc = C_; }
    else                 { src = W_w;  dst = WT;  Cc = I_; }
    int R = (C_*I_) / Cc;
    int r = idx / Cc, c2 = idx % Cc;
    dst[c2 * R + r] = src[idx];
}

// three convs on x in one dispatch: z = proj*8 + f, y = i-block(32)
__global__ __launch_bounds__(256) void k_conv3(const float* __restrict__ x,
                                               const float* __restrict__ w0,
                                               const float* __restrict__ w1,
                                               const float* __restrict__ w2,
                                               const float* __restrict__ b0,
                                               const float* __restrict__ b1,
                                               const float* __restrict__ b2,
                                               float* __restrict__ o0,
                                               float* __restrict__ o1,
                                               float* __restrict__ o2) {
    int p  = blockIdx.x * 256 + threadIdx.x;
    int i0 = blockIdx.y * 32;
    int z  = blockIdx.z; int proj = z >> 3; int f = z & 7;
    const float* wT   = proj == 0 ? w0 : (proj == 1 ? w1 : w2);
    const float* bias = proj == 0 ? b0 : (proj == 1 ? b1 : b2);
    float* out        = proj == 0 ? o0 : (proj == 1 ? o1 : o2);
    const float* xp = x + (size_t)f * C_ * P_ + p;
    float acc[32];
#pragma unroll
    for (int ii = 0; ii < 32; ++ii) acc[ii] = 0.f;
    for (int c = 0; c < C_; ++c) {
        float xv = xp[(size_t)c * P_];
        const float* wr = wT + (size_t)c * I_ + i0;   // uniform -> s_load
#pragma unroll
        for (int ii = 0; ii < 32; ++ii) acc[ii] += xv * wr[ii];
    }
    float* op = out + ((size_t)f * I_ + i0) * P_ + p;
#pragma unroll
    for (int ii = 0; ii < 32; ++ii) op[(size_t)ii * P_] = acc[ii] + bias[i0 + ii];
}

// GRW[c][p] = Kc[c] + sum_cc MT[cc][c]*rgb[cc][p]   (Cin=128 -> Cout=128)
__global__ __launch_bounds__(256) void k_grw(const float* __restrict__ rgb,
                                             const float* __restrict__ MT,
                                             const float* __restrict__ Kc,
                                             float* __restrict__ GRW) {
    int p  = blockIdx.x * 256 + threadIdx.x;
    int c0 = blockIdx.y * 32;
    float acc[32];
#pragma unroll
    for (int ii = 0; ii < 32; ++ii) acc[ii] = 0.f;
    for (int c = 0; c < C_; ++c) {
        float xv = rgb[(size_t)c * P_ + p];
        const float* wr = MT + (size_t)c * C_ + c0;
#pragma unroll
        for (int ii = 0; ii < 32; ++ii) acc[ii] += xv * wr[ii];
    }
#pragma unroll
    for (int ii = 0; ii < 32; ++ii) GRW[(size_t)(c0 + ii) * P_ + p] = acc[ii] + Kc[c0 + ii];
}

// y<8: Bf[f][p] = ct1 + sum_c x[f,c,p]*u[c];  y==8: SR[p] = ct0 + sum_c rgb[c,p]*vt[c]
__global__ __launch_bounds__(256) void k_fields(const float* __restrict__ rgb,
                                                const float* __restrict__ x,
                                                const float* __restrict__ vt,
                                                const float* __restrict__ u,
                                                const float* __restrict__ ct,
                                                float* __restrict__ SR,
                                                float* __restrict__ Bf) {
    int p = blockIdx.x * 256 + threadIdx.x;
    int y = blockIdx.y;
    if (y == 8) {
        float s = ct[0];
        for (int c = 0; c < C_; ++c) s += rgb[(size_t)c * P_ + p] * vt[c];
        SR[p] = s;
    } else {
        float b2 = ct[1];
        const float* xp = x + (size_t)y * C_ * P_ + p;
        for (int c = 0; c < C_; ++c) b2 += xp[(size_t)c * P_] * u[c];
        Bf[y * P_ + p] = b2;
    }
}

// scores: S[f1][k][p] = sum_i PH[f1][i][p] * TH[f2(k)][i][q_k]; 8 k per block
__global__ __launch_bounds__(256) void k_scores(const float* __restrict__ PH,
                                                const float* __restrict__ TH,
                                                float* __restrict__ S) {
    int p  = blockIdx.x * 256 + threadIdx.x;
    int k0 = blockIdx.y * 8;
    int px = p % W_, py = p / W_;
    size_t tb[8]; float msk[8];
#pragma unroll
    for (int kk = 0; kk < 8; ++kk) {
        int k  = k0 + kk;
        int f2 = k / T_;
        int t  = k - f2 * T_;
        int dy = c_dy[t], dx = c_dx[t];
        bool v = ((unsigned)(py + dy) < H_) && ((unsigned)(px + dx) < W_);
        int q  = p + dy * W_ + dx;
        q = min(max(q, 0), P_ - 1);
        tb[kk]  = (size_t)f2 * I_ * P_ + q;
        msk[kk] = v ? 1.f : 0.f;
    }
    float acc[8][8];
#pragma unroll
    for (int a = 0; a < 8; ++a)
#pragma unroll
        for (int b = 0; b < 8; ++b) acc[a][b] = 0.f;
    for (int i = 0; i < I_; ++i) {
        float phv[8];
#pragma unroll
        for (int f1 = 0; f1 < 8; ++f1) phv[f1] = PH[((size_t)f1 * I_ + i) * P_ + p];
#pragma unroll
        for (int kk = 0; kk < 8; ++kk) {
            float tv = TH[tb[kk] + (size_t)i * P_] * msk[kk];
#pragma unroll
            for (int f1 = 0; f1 < 8; ++f1) acc[f1][kk] += phv[f1] * tv;
        }
    }
#pragma unroll
    for (int f1 = 0; f1 < 8; ++f1)
#pragma unroll
        for (int kk = 0; kk < 8; ++kk)
            S[((size_t)f1 * KK_ + k0 + kk) * P_ + p] = acc[f1][kk];
}

__global__ __launch_bounds__(128) void k_softmax(float* __restrict__ S,
                                                 float* __restrict__ den) {
    int p  = blockIdx.x * 128 + threadIdx.x;
    int f1 = blockIdx.y;
    float* sp = S + (size_t)f1 * KK_ * P_ + p;
    float m = -1e30f;
    for (int k = 0; k < KK_; ++k) m = fmaxf(m, sp[(size_t)k * P_]);
    float s = 0.f;
    for (int k = 0; k < KK_; ++k) {
        float e = __expf(sp[(size_t)k * P_] - m);
        sp[(size_t)k * P_] = e;
        s += e;
    }
    den[f1 * P_ + p] = 1.f / s;
}

// Y[f1][i][p] = (sum_k Sexp * G[f2][i][q]) * den;  2 f1 x 8 i per thread
__global__ __launch_bounds__(256) void k_y(const float* __restrict__ S,
                                           const float* __restrict__ G,
                                           const float* __restrict__ den,
                                           float* __restrict__ Y) {
    int p   = blockIdx.x * 256 + threadIdx.x;
    int f10 = blockIdx.y * 2;
    int i0  = blockIdx.z * 8;
    int px = p % W_, py = p / W_;
    float acc[2][8];
#pragma unroll
    for (int a = 0; a < 2; ++a)
#pragma unroll
        for (int b = 0; b < 8; ++b) acc[a][b] = 0.f;
    for (int f2 = 0; f2 < F_; ++f2) {
        const float* gb = G + ((size_t)f2 * I_ + i0) * P_;
#pragma unroll
        for (int t = 0; t < T_; ++t) {
            int k  = f2 * T_ + t;
            int dy = c_dy[t], dx = c_dx[t];
            bool v = ((unsigned)(py + dy) < H_) && ((unsigned)(px + dx) < W_);
            int q  = p + dy * W_ + dx;
            q = min(max(q, 0), P_ - 1);
            float m = v ? 1.f : 0.f;
            float av[2];
#pragma unroll
            for (int ff = 0; ff < 2; ++ff)
                av[ff] = S[((size_t)(f10 + ff) * KK_ + k) * P_ + p];
            float gv[8];
#pragma unroll
            for (int ii = 0; ii < 8; ++ii)
                gv[ii] = gb[(size_t)ii * P_ + q] * m;
#pragma unroll
            for (int ff = 0; ff < 2; ++ff)
#pragma unroll
                for (int ii = 0; ii < 8; ++ii) acc[ff][ii] += av[ff] * gv[ii];
        }
    }
#pragma unroll
    for (int ff = 0; ff < 2; ++ff) {
        float dv = den[(f10 + ff) * P_ + p];
#pragma unroll
        for (int ii = 0; ii < 8; ++ii)
            Y[((size_t)(f10 + ff) * I_ + i0 + ii) * P_ + p] = acc[ff][ii] * dv;
    }
}

// out[f][c][p] = sum_i Y[f][i][p]*WT[i][c] + sum_t fr[f][t][p]*GRW[c][q_t]
//               + Wb[c] + rWb[c] + x[f][c][p]
__global__ __launch_bounds__(256) void k_final(const float* __restrict__ Y,
                                               const float* __restrict__ WT,
                                               const float* __restrict__ Wb,
                                               const float* __restrict__ rWb,
                                               const float* __restrict__ SR,
                                               const float* __restrict__ Bf,
                                               const float* __restrict__ GRW,
                                               const float* __restrict__ x,
                                               float* __restrict__ out) {
    int p  = blockIdx.x * 256 + threadIdx.x;
    int f  = blockIdx.y;
    int c0 = blockIdx.z * 32;
    int px = p % W_, py = p / W_;
    float bv = Bf[f * P_ + p];
    float fr[T_]; int qs[T_];
#pragma unroll
    for (int t = 0; t < T_; ++t) {
        int dy = c_dy[t], dx = c_dx[t];
        bool v = ((unsigned)(py + dy) < H_) && ((unsigned)(px + dx) < W_);
        int q  = p + dy * W_ + dx;
        q = min(max(q, 0), P_ - 1);
        qs[t] = q;
        fr[t] = v ? fmaxf(SR[q] + bv, 0.f) * (1.f / (float)T_) : 0.f;
    }
    float acc[32];
#pragma unroll
    for (int cc = 0; cc < 32; ++cc) acc[cc] = 0.f;
    const float* yp = Y + (size_t)f * I_ * P_ + p;
    for (int i = 0; i < I_; ++i) {
        float yv = yp[(size_t)i * P_];
        const float* wr = WT + (size_t)i * C_ + c0;   // uniform -> s_load
#pragma unroll
        for (int cc = 0; cc < 32; ++cc) acc[cc] += yv * wr[cc];
    }
#pragma unroll
    for (int t = 0; t < T_; ++t) {
        float fv = fr[t];
        const float* gp = GRW + qs[t];
#pragma unroll
        for (int cc = 0; cc < 32; ++cc)
            acc[cc] += fv * gp[(size_t)(c0 + cc) * P_];
    }
#pragma unroll
    for (int cc = 0; cc < 32; ++cc) {
        size_t o = ((size_t)f * C_ + c0 + cc) * P_ + p;
        out[o] = acc[cc] + Wb[c0 + cc] + rWb[c0 + cc] + x[o];
    }
}

extern "C" void kernel_launch(void* const* d_in, const int* in_sizes, int n_in,
                              void* d_out, int out_size, void* d_ws, size_t ws_size,
                              hipStream_t stream) {
    const float* x    = (const float*)d_in[0];
    const float* rgb  = (const float*)d_in[1];
    const float* g_w  = (const float*)d_in[2];
    const float* g_b  = (const float*)d_in[3];
    const float* th_w = (const float*)d_in[4];
    const float* th_b = (const float*)d_in[5];
    const float* ph_w = (const float*)d_in[6];
    const float* ph_b = (const float*)d_in[7];
    const float* W_w  = (const float*)d_in[8];
    const float* W_b  = (const float*)d_in[9];
    const float* rg_w = (const float*)d_in[10];
    const float* rg_b = (const float*)d_in[11];
    const float* rt_w = (const float*)d_in[12];
    const float* rt_b = (const float*)d_in[13];
    const float* rp_w = (const float*)d_in[14];
    const float* rp_b = (const float*)d_in[15];
    const float* rW_w = (const float*)d_in[16];
    const float* rW_b = (const float*)d_in[17];
    const float* cp_w = (const float*)d_in[18];
    float* out = (float*)d_out;

    const size_t FIP = (size_t)F_ * I_ * P_;   // 4718592
    const size_t SKP = (size_t)F_ * KK_ * P_;  // 10027008

    float* ws  = (float*)d_ws;
    float* G   = ws;
    float* TH  = G + FIP;
    float* PH  = TH + FIP;
    float* S   = PH + FIP;
    float* DEN = S + SKP;
    float* SR  = DEN + (size_t)F_ * P_;
    float* Bf  = SR + P_;
    float* VT  = Bf + (size_t)F_ * P_;
    float* U   = VT + C_;
    float* CT  = U + C_;
    float* Kc  = CT + 2;
    float* MT  = Kc + C_;
    float* gT  = MT + (size_t)C_ * C_;
    float* thT = gT + (size_t)C_ * I_;
    float* phT = thT + (size_t)C_ * I_;
    float* WT  = phT + (size_t)C_ * I_;
    float* Y   = TH;   // alias: TH dead after k_scores
    float* GRW = PH;   // alias: PH dead after k_scores (k_grw runs after k_scores)

    // weight prep
    k_prep<<<1, 128, 0, stream>>>(rt_w, rp_w, rt_b, rp_b, cp_w, rW_w, rg_b, VT, U, CT, Kc);
    k_mt<<<128, 128, 0, stream>>>(rW_w, rg_w, MT);
    k_tr<<<dim3(32, 4), 256, 0, stream>>>(g_w, th_w, ph_w, W_w, gT, thT, phT, WT);

    // projections of x: G, TH, PH in one dispatch
    k_conv3<<<dim3(P_ / 256, 2, 24), 256, 0, stream>>>(x, gT, thT, phT,
                                                       g_b, th_b, ph_b, G, TH, PH);

    // scalar fields
    k_fields<<<dim3(P_ / 256, 9), 256, 0, stream>>>(rgb, x, VT, U, CT, SR, Bf);

    // attention scores + softmax
    k_scores<<<dim3(P_ / 256, KK_ / 8), 256, 0, stream>>>(PH, TH, S);

    // GRW after k_scores (PH region reuse)
    k_grw<<<dim3(P_ / 256, 4), 256, 0, stream>>>(rgb, MT, Kc, GRW);

    k_softmax<<<dim3(P_ / 128, F_), 128, 0, stream>>>(S, DEN);

    // attention apply
    k_y<<<dim3(P_ / 256, F_ / 2, I_ / 8), 256, 0, stream>>>(S, G, DEN, Y);

    // final: W*Y + rgb-branch + biases + residual
    k_final<<<dim3(P_ / 256, F_, C_ / 32), 256, 0, stream>>>(Y, WT, W_b, rW_b,
                                                             SR, Bf, GRW, x, out);
}